// Round 11
// baseline (425.796 us; speedup 1.0000x reference)
//
#include <hip/hip_runtime.h>
#include <hip/hip_bf16.h>
#include <math.h>

// Problem constants (B=2, C=256, H=W=64, D=4, K=9, K2=81)
#define BATCH 2
#define CCH   256
#define HH    64
#define WW    64
#define PIX   (HH*WW)          // 4096
#define K2    81
#define BP_N  (BATCH*PIX)      // 8192

// ---------------------------------------------------------------------------
// NCHW -> NHWC tiled transpose (per batch).  in: [B][C][P]  out: [B][P][C]
// ---------------------------------------------------------------------------
__global__ void k_transpose(const float* __restrict__ in, float* __restrict__ out) {
    __shared__ float tile[32][33];
    int b  = blockIdx.z;
    int p0 = blockIdx.x * 32;
    int c0 = blockIdx.y * 32;
    int tx = threadIdx.x;     // 32
    int ty = threadIdx.y;     // 8
    const float* ib = in  + (size_t)b * CCH * PIX;
    float*       ob = out + (size_t)b * CCH * PIX;
    #pragma unroll
    for (int i = 0; i < 4; i++) {
        int c = c0 + ty + i * 8;
        int p = p0 + tx;
        tile[ty + i * 8][tx] = ib[(size_t)c * PIX + p];
    }
    __syncthreads();
    #pragma unroll
    for (int i = 0; i < 4; i++) {
        int p = p0 + ty + i * 8;
        int c = c0 + tx;
        ob[(size_t)p * CCH + c] = tile[tx][ty + i * 8];
    }
}

// ---------------------------------------------------------------------------
// Correlation + sum-normalize + assemble — BIT-EXACT recipe, code copied
// verbatim from the R9-verified kernel (passed R7-R10, absmax 16384/19988):
// per-dot, lane j accumulates c=32t+j (t ascending, fmaf); combine =
// xor-{8,16,4,2,1} butterfly, lane-0 value; k-sum sequential ascending;
// fp32 divide; assemble sequential ascending-k FMA.  DO NOT CHANGE ROUNDING.
//
// R11: the only change vs R9 is REMOVING the alignedN[b][c][p] scattered
// store (measured WRITE_SIZE 80 MB vs 8 MB useful, 5x amplification);
// aligned stays NHWC-only and k_blend transposes on the fly.
// ---------------------------------------------------------------------------
__global__ void k_corr_assemble(const float* __restrict__ featT,
                                const float* __restrict__ refT,
                                float* __restrict__ alignedT) {
    int bp = blockIdx.x;               // 0..8191
    int b  = bp >> 12;
    int p  = bp & 4095;
    int h  = p >> 6, w = p & 63;
    int tid = threadIdx.x;             // 0..255

    __shared__ float s_feat[256];
    __shared__ float s_aff[K2];
    __shared__ float s_affn[K2];
    __shared__ int   s_pix[K2];
    __shared__ float s_den;

    s_feat[tid] = featT[((size_t)bp << 8) + tid];
    if (tid < K2) {
        int dy = tid / 9, dx = tid - dy * 9;
        int y = h + dy - 4, x = w + dx - 4;
        s_pix[tid] = ((unsigned)y < 64u && (unsigned)x < 64u) ? ((y << 6) | x) : -1;
    }
    __syncthreads();

    const float* rb = refT + ((size_t)b << 20);   // b*4096*256

    // Phase 1: lane-parallel strided partials + butterfly combine.
    int hw = tid >> 5;        // 0..7
    int j  = tid & 31;        // 0..31
    for (int it = 0; it < 11; it++) {
        int k = it * 8 + hw;
        float partial = 0.f;
        int pix = (k < K2) ? s_pix[k] : -1;
        if (pix >= 0) {
            const float* rp = rb + ((size_t)pix << 8);
            #pragma unroll
            for (int t = 0; t < 8; t++) {
                int c = 32 * t + j;
                partial = fmaf(s_feat[c], rp[c], partial);
            }
        }
        partial = __fadd_rn(partial, __shfl_xor(partial, 8));
        partial = __fadd_rn(partial, __shfl_xor(partial, 16));
        partial = __fadd_rn(partial, __shfl_xor(partial, 4));
        partial = __fadd_rn(partial, __shfl_xor(partial, 2));
        partial = __fadd_rn(partial, __shfl_xor(partial, 1));
        if (j == 0 && k < K2) s_aff[k] = partial;
    }
    __syncthreads();

    // Phase 2: s = sequential ascending-k fp32 add chain; den = s + 1e-7f
    if (tid == 0) {
        float s = 0.f;
        for (int k = 0; k < K2; k++) s = __fadd_rn(s, s_aff[k]);
        s_den = __fadd_rn(s, 1e-7f);
    }
    __syncthreads();
    if (tid < K2) s_affn[tid] = __fdiv_rn(s_aff[tid], s_den);
    __syncthreads();

    // Phase 3: aligned[c] = sequential ascending-k FMA chain (coalesced)
    int c = tid;
    float acc = 0.f;
    for (int k = 0; k < K2; k++) {
        int pix = s_pix[k];
        if (pix >= 0)
            acc = fmaf(s_affn[k], rb[((size_t)pix << 8) + c], acc);
    }
    alignedT[((size_t)bp << 8) + c] = acc;
}

// ---------------------------------------------------------------------------
// Conv1: 1x1, 512 -> 256, FP32 GEMM (numerics-free stage).
// M=8192 px, N=256 o, K=512 (cat = [featT | alignedT]).  64x64 tile, K-chunks
// of 32, 256 thr, 4x4 acc/thread.  LDS staged with +65 pad (bank-conflict
// free both on store and the broadcasty compute reads).  Replaces the R8
// version whose per-o weight loads were 64-way scattered per wave.
// ---------------------------------------------------------------------------
__global__ void k_conv1(const float* __restrict__ featT,
                        const float* __restrict__ alignedT,
                        const float* __restrict__ w1,
                        const float* __restrict__ b1,
                        float* __restrict__ h1) {
    __shared__ float s_a[32][65];
    __shared__ float s_b[32][65];
    int m0  = blockIdx.x * 64;        // pixel base
    int n0  = blockIdx.y * 64;        // out-channel base
    int tid = threadIdx.x;
    int tx  = tid & 15;               // n group (4 o each)
    int ty  = tid >> 4;               // m group (4 px each)

    float acc[4][4] = {{0.f}};

    for (int kc = 0; kc < 16; kc++) {
        int c0 = kc * 32;
        const float* asrc;
        int coff;
        if (c0 < 256) { asrc = featT;    coff = c0; }
        else          { asrc = alignedT; coff = c0 - 256; }

        for (int i = tid; i < 64 * 32; i += 256) {
            int px = i >> 5, cc = i & 31;
            s_a[cc][px] = asrc[((size_t)(m0 + px) << 8) + coff + cc];
        }
        for (int i = tid; i < 64 * 32; i += 256) {
            int o = i >> 5, cc = i & 31;
            s_b[cc][o] = w1[(size_t)(n0 + o) * 512 + c0 + cc];
        }
        __syncthreads();

        #pragma unroll 8
        for (int k = 0; k < 32; k++) {
            float av[4], bv[4];
            #pragma unroll
            for (int i = 0; i < 4; i++) av[i] = s_a[k][ty * 4 + i];
            #pragma unroll
            for (int jj = 0; jj < 4; jj++) bv[jj] = s_b[k][tx * 4 + jj];
            #pragma unroll
            for (int i = 0; i < 4; i++)
                #pragma unroll
                for (int jj = 0; jj < 4; jj++)
                    acc[i][jj] = fmaf(av[i], bv[jj], acc[i][jj]);
        }
        __syncthreads();
    }

    float4 bias = *(const float4*)(b1 + n0 + tx * 4);
    #pragma unroll
    for (int i = 0; i < 4; i++) {
        int px = m0 + ty * 4 + i;
        float4 v;
        v.x = acc[i][0] + bias.x;
        v.y = acc[i][1] + bias.y;
        v.z = acc[i][2] + bias.z;
        v.w = acc[i][3] + bias.w;
        *(float4*)(h1 + ((size_t)px << 8) + n0 + tx * 4) = v;
    }
}

// ---------------------------------------------------------------------------
// w2 [16][256][3][3] (o,c,kk) -> w2t [kk][o][c]  (c contiguous per thread)
// ---------------------------------------------------------------------------
__global__ void k_w2t(const float* __restrict__ w2, float* __restrict__ w2t) {
    int i = blockIdx.x * 256 + threadIdx.x;
    if (i >= 16 * 256 * 9) return;
    int o  = i / 2304;
    int r  = i % 2304;         // c*9 + kk
    int c  = r / 9;
    int kk = r % 9;
    w2t[((size_t)(kk * 16 + o) << 8) + c] = w2[i];
}

// ---------------------------------------------------------------------------
// Conv2: 3x3 pad1, 256 -> 16, FP32, numerics-free.  R11: 16-px tiles
// (grid 512, LDS 14.7 KB) — the R9 32-px version was grid-256 = 1 block/CU
// latency-bound.  Thread = (o, px); c in 4 chunks of 64 staged w/ halo.
// ---------------------------------------------------------------------------
__global__ void k_conv2(const float* __restrict__ h1,
                        const float* __restrict__ w2t,
                        const float* __restrict__ b2,
                        float* __restrict__ h2) {
    __shared__ float s_in[3][18][68];
    int blk = blockIdx.x;          // 0..511
    int b   = blk >> 8;            // 256 blocks per batch
    int r   = blk & 255;
    int y   = r >> 2;
    int w0  = (r & 3) * 16;
    int tid = threadIdx.x;
    int o   = tid & 15;
    int ps  = tid >> 4;            // 0..15, one pixel each

    const float* hb = h1 + ((size_t)b << 20);

    float4 a0 = {0.f, 0.f, 0.f, 0.f};

    for (int chunk = 0; chunk < 4; chunk++) {
        int c0 = chunk << 6;
        for (int i = tid; i < 3 * 18 * 16; i += 256) {   // 864 float4 loads
            int c4 = i & 15;
            int pi = (i >> 4) % 18;
            int ri = (i >> 4) / 18;
            int yy = y + ri - 1;
            int xx = w0 + pi - 1;
            float4 v = {0.f, 0.f, 0.f, 0.f};
            if ((unsigned)yy < 64u && (unsigned)xx < 64u)
                v = *(const float4*)(hb + ((size_t)((yy << 6) | xx) << 8) + c0 + (c4 << 2));
            *(float4*)&s_in[ri][pi][c4 << 2] = v;
        }
        __syncthreads();

        #pragma unroll
        for (int kk = 0; kk < 9; kk++) {
            int ky = kk / 3, kx = kk - ky * 3;
            const float* wp = w2t + (((size_t)(kk * 16 + o)) << 8) + c0;
            #pragma unroll 8
            for (int c4 = 0; c4 < 16; c4++) {
                float4 wv = *(const float4*)(wp + (c4 << 2));
                float4 iv = *(const float4*)&s_in[ky][ps + kx][c4 << 2];
                a0.x = fmaf(wv.x, iv.x, a0.x);
                a0.y = fmaf(wv.y, iv.y, a0.y);
                a0.z = fmaf(wv.z, iv.z, a0.z);
                a0.w = fmaf(wv.w, iv.w, a0.w);
            }
        }
        __syncthreads();
    }

    size_t bp = ((size_t)b << 12) + (y << 6) + w0 + ps;
    h2[bp * 16 + o] = ((a0.x + a0.y) + (a0.z + a0.w)) + b2[o];
}

// ---------------------------------------------------------------------------
// Conv3: 3x3 pad1, 16 -> 3, FP32, numerics-free.  Thread per pixel.
// ---------------------------------------------------------------------------
__global__ void k_conv3(const float* __restrict__ h2,
                        const float* __restrict__ w3,
                        const float* __restrict__ b3,
                        float* __restrict__ h3) {
    int bp = blockIdx.x * 256 + threadIdx.x;
    if (bp >= BP_N) return;
    int b = bp >> 12;
    int p = bp & 4095;
    int h = p >> 6, w = p & 63;
    const float* hb = h2 + ((size_t)b << 16);   // b*4096*16

    float a0 = 0.f, a1 = 0.f, a2 = 0.f;
    #pragma unroll
    for (int kk = 0; kk < 9; kk++) {
        int ky = kk / 3, kx = kk - ky * 3;
        int y = h + ky - 1, x = w + kx - 1;
        if ((unsigned)y >= 64u || (unsigned)x >= 64u) continue;
        const float* ip = hb + (size_t)((y << 6) | x) * 16;
        #pragma unroll
        for (int c = 0; c < 16; c++) {
            float v = ip[c];
            int wi = c * 9 + kk;
            a0 = fmaf(w3[wi],       v, a0);
            a1 = fmaf(w3[144 + wi], v, a1);
            a2 = fmaf(w3[288 + wi], v, a2);
        }
    }
    h3[(size_t)bp * 3 + 0] = a0 + b3[0];
    h3[(size_t)bp * 3 + 1] = a1 + b3[1];
    h3[(size_t)bp * 3 + 2] = a2 + b3[2];
}

// ---------------------------------------------------------------------------
// Conv4 (3x3, 3 -> 2) + softmax -> (score0, score1), FP32, numerics-free.
// ---------------------------------------------------------------------------
__global__ void k_score(const float* __restrict__ h3,
                        const float* __restrict__ w4,
                        const float* __restrict__ b4,
                        float2* __restrict__ score) {
    int bp = blockIdx.x * 256 + threadIdx.x;
    if (bp >= BP_N) return;
    int b = bp >> 12;
    int p = bp & 4095;
    int h = p >> 6, w = p & 63;
    const float* hb = h3 + (size_t)b * PIX * 3;

    float l0 = 0.f, l1 = 0.f;
    #pragma unroll
    for (int kk = 0; kk < 9; kk++) {
        int ky = kk / 3, kx = kk - ky * 3;
        int y = h + ky - 1, x = w + kx - 1;
        if ((unsigned)y >= 64u || (unsigned)x >= 64u) continue;
        const float* ip = hb + (size_t)((y << 6) | x) * 3;
        #pragma unroll
        for (int c = 0; c < 3; c++) {
            float v = ip[c];
            int wi = c * 9 + kk;
            l0 = fmaf(w4[wi],      v, l0);
            l1 = fmaf(w4[27 + wi], v, l1);
        }
    }
    l0 += b4[0];
    l1 += b4[1];

    float m  = fmaxf(l0, l1);
    float e0 = expf(l0 - m);
    float e1 = expf(l1 - m);
    float s  = e0 + e1;
    score[bp] = make_float2(e0 / s, e1 / s);
}

// ---------------------------------------------------------------------------
// Blend + on-the-fly NHWC->NCHW transpose of aligned (replaces the alignedN
// materialization): out[b][c][p] = s0*feat + s1*aligned.  Blend arithmetic
// identical to the verified version (__fmul_rn/__fmul_rn/__fadd_rn).
// ---------------------------------------------------------------------------
__global__ void k_blend(const float* __restrict__ feat,
                        const float* __restrict__ alignedT,
                        const float2* __restrict__ score,
                        float* __restrict__ out) {
    __shared__ float tile[32][33];
    int b  = blockIdx.z;
    int p0 = blockIdx.x * 32;
    int c0 = blockIdx.y * 32;
    int tx = threadIdx.x;     // 32
    int ty = threadIdx.y;     // 8

    const float* at = alignedT + ((size_t)b << 20);
    #pragma unroll
    for (int i = 0; i < 4; i++) {
        int p = p0 + ty + i * 8;
        tile[ty + i * 8][tx] = at[((size_t)p << 8) + c0 + tx];
    }
    __syncthreads();

    int p = p0 + tx;
    float2 s = score[(b << 12) + p];
    #pragma unroll
    for (int i = 0; i < 4; i++) {
        int c = c0 + ty + i * 8;
        size_t idx = (((size_t)(b * 256 + c)) << 12) + p;
        out[idx] = __fadd_rn(__fmul_rn(s.x, feat[idx]),
                             __fmul_rn(s.y, tile[tx][ty + i * 8]));
    }
}

// ---------------------------------------------------------------------------
extern "C" void kernel_launch(void* const* d_in, const int* in_sizes, int n_in,
                              void* d_out, int out_size, void* d_ws, size_t ws_size,
                              hipStream_t stream) {
    const float* feat     = (const float*)d_in[0];
    const float* feat_ref = (const float*)d_in[1];
    const float* w1 = (const float*)d_in[2];
    const float* b1 = (const float*)d_in[3];
    const float* w2 = (const float*)d_in[4];
    const float* b2 = (const float*)d_in[5];
    const float* w3 = (const float*)d_in[6];
    const float* b3 = (const float*)d_in[7];
    const float* w4 = (const float*)d_in[8];
    const float* b4 = (const float*)d_in[9];
    float* out = (float*)d_out;

    const size_t NCP = (size_t)BATCH * CCH * PIX;   // 2,097,152
    char* wsb = (char*)d_ws;
    float*  featT    = (float*)wsb;   wsb += NCP * 4;               // 8 MB
    float*  refT     = (float*)wsb;   wsb += NCP * 4;               // 8 MB
    float*  alignedT = (float*)wsb;   wsb += NCP * 4;               // 8 MB
    float*  h1       = (float*)wsb;   wsb += NCP * 4;               // 8 MB
    float*  h2       = (float*)wsb;   wsb += (size_t)BP_N * 16 * 4;
    float*  h3       = (float*)wsb;   wsb += (size_t)BP_N * 3 * 4;
    float2* sc       = (float2*)wsb;  wsb += (size_t)BP_N * 8;
    float*  w2t      = (float*)wsb;   wsb += (size_t)16 * 256 * 9 * 4;

    dim3 tb(32, 8, 1);
    dim3 tg(PIX / 32, CCH / 32, BATCH);
    k_transpose<<<tg, tb, 0, stream>>>(feat, featT);
    k_transpose<<<tg, tb, 0, stream>>>(feat_ref, refT);
    k_w2t<<<144, 256, 0, stream>>>(w2, w2t);

    k_corr_assemble<<<BP_N, 256, 0, stream>>>(featT, refT, alignedT);
    k_conv1<<<dim3(BP_N / 64, 256 / 64, 1), 256, 0, stream>>>(featT, alignedT, w1, b1, h1);
    k_conv2<<<BP_N / 16, 256, 0, stream>>>(h1, w2t, b2, h2);
    k_conv3<<<BP_N / 256, 256, 0, stream>>>(h2, w3, b3, h3);
    k_score<<<BP_N / 256, 256, 0, stream>>>(h3, w4, b4, sc);
    k_blend<<<tg, tb, 0, stream>>>(feat, alignedT, sc, out);
}

// Round 12
// 336.392 us; speedup vs baseline: 1.2658x; 1.2658x over previous
//
#include <hip/hip_runtime.h>
#include <hip/hip_bf16.h>
#include <math.h>

// Problem constants (B=2, C=256, H=W=64, D=4, K=9, K2=81)
#define BATCH 2
#define CCH   256
#define HH    64
#define WW    64
#define PIX   (HH*WW)          // 4096
#define K2    81
#define BP_N  (BATCH*PIX)      // 8192

// ---------------------------------------------------------------------------
// NCHW -> NHWC tiled transpose (per batch).  in: [B][C][P]  out: [B][P][C]
// ---------------------------------------------------------------------------
__global__ void k_transpose(const float* __restrict__ in, float* __restrict__ out) {
    __shared__ float tile[32][33];
    int b  = blockIdx.z;
    int p0 = blockIdx.x * 32;
    int c0 = blockIdx.y * 32;
    int tx = threadIdx.x;     // 32
    int ty = threadIdx.y;     // 8
    const float* ib = in  + (size_t)b * CCH * PIX;
    float*       ob = out + (size_t)b * CCH * PIX;
    #pragma unroll
    for (int i = 0; i < 4; i++) {
        int c = c0 + ty + i * 8;
        int p = p0 + tx;
        tile[ty + i * 8][tx] = ib[(size_t)c * PIX + p];
    }
    __syncthreads();
    #pragma unroll
    for (int i = 0; i < 4; i++) {
        int p = p0 + ty + i * 8;
        int c = c0 + tx;
        ob[(size_t)p * CCH + c] = tile[tx][ty + i * 8];
    }
}

// ---------------------------------------------------------------------------
// Correlation + sum-normalize + assemble — BIT-EXACT recipe (passed R7-R11,
// absmax 16384/19988).  DO NOT CHANGE ANY ROUNDING.  Verbatim from R11.
// ---------------------------------------------------------------------------
__global__ void k_corr_assemble(const float* __restrict__ featT,
                                const float* __restrict__ refT,
                                float* __restrict__ alignedT) {
    int bp = blockIdx.x;               // 0..8191
    int b  = bp >> 12;
    int p  = bp & 4095;
    int h  = p >> 6, w = p & 63;
    int tid = threadIdx.x;             // 0..255

    __shared__ float s_feat[256];
    __shared__ float s_aff[K2];
    __shared__ float s_affn[K2];
    __shared__ int   s_pix[K2];
    __shared__ float s_den;

    s_feat[tid] = featT[((size_t)bp << 8) + tid];
    if (tid < K2) {
        int dy = tid / 9, dx = tid - dy * 9;
        int y = h + dy - 4, x = w + dx - 4;
        s_pix[tid] = ((unsigned)y < 64u && (unsigned)x < 64u) ? ((y << 6) | x) : -1;
    }
    __syncthreads();

    const float* rb = refT + ((size_t)b << 20);   // b*4096*256

    // Phase 1: lane-parallel strided partials + butterfly combine.
    int hw = tid >> 5;        // 0..7
    int j  = tid & 31;        // 0..31
    for (int it = 0; it < 11; it++) {
        int k = it * 8 + hw;
        float partial = 0.f;
        int pix = (k < K2) ? s_pix[k] : -1;
        if (pix >= 0) {
            const float* rp = rb + ((size_t)pix << 8);
            #pragma unroll
            for (int t = 0; t < 8; t++) {
                int c = 32 * t + j;
                partial = fmaf(s_feat[c], rp[c], partial);
            }
        }
        partial = __fadd_rn(partial, __shfl_xor(partial, 8));
        partial = __fadd_rn(partial, __shfl_xor(partial, 16));
        partial = __fadd_rn(partial, __shfl_xor(partial, 4));
        partial = __fadd_rn(partial, __shfl_xor(partial, 2));
        partial = __fadd_rn(partial, __shfl_xor(partial, 1));
        if (j == 0 && k < K2) s_aff[k] = partial;
    }
    __syncthreads();

    // Phase 2: s = sequential ascending-k fp32 add chain; den = s + 1e-7f
    if (tid == 0) {
        float s = 0.f;
        for (int k = 0; k < K2; k++) s = __fadd_rn(s, s_aff[k]);
        s_den = __fadd_rn(s, 1e-7f);
    }
    __syncthreads();
    if (tid < K2) s_affn[tid] = __fdiv_rn(s_aff[tid], s_den);
    __syncthreads();

    // Phase 3: aligned[c] = sequential ascending-k FMA chain (coalesced)
    int c = tid;
    float acc = 0.f;
    for (int k = 0; k < K2; k++) {
        int pix = s_pix[k];
        if (pix >= 0)
            acc = fmaf(s_affn[k], rb[((size_t)pix << 8) + c], acc);
    }
    alignedT[((size_t)bp << 8) + c] = acc;
}

// ---------------------------------------------------------------------------
// Conv1: 1x1, 512 -> 256, FP32 GEMM (numerics-free).  Verbatim from R11.
// ---------------------------------------------------------------------------
__global__ void k_conv1(const float* __restrict__ featT,
                        const float* __restrict__ alignedT,
                        const float* __restrict__ w1,
                        const float* __restrict__ b1,
                        float* __restrict__ h1) {
    __shared__ float s_a[32][65];
    __shared__ float s_b[32][65];
    int m0  = blockIdx.x * 64;        // pixel base
    int n0  = blockIdx.y * 64;        // out-channel base
    int tid = threadIdx.x;
    int tx  = tid & 15;               // n group (4 o each)
    int ty  = tid >> 4;               // m group (4 px each)

    float acc[4][4] = {{0.f}};

    for (int kc = 0; kc < 16; kc++) {
        int c0 = kc * 32;
        const float* asrc;
        int coff;
        if (c0 < 256) { asrc = featT;    coff = c0; }
        else          { asrc = alignedT; coff = c0 - 256; }

        for (int i = tid; i < 64 * 32; i += 256) {
            int px = i >> 5, cc = i & 31;
            s_a[cc][px] = asrc[((size_t)(m0 + px) << 8) + coff + cc];
        }
        for (int i = tid; i < 64 * 32; i += 256) {
            int o = i >> 5, cc = i & 31;
            s_b[cc][o] = w1[(size_t)(n0 + o) * 512 + c0 + cc];
        }
        __syncthreads();

        #pragma unroll 8
        for (int k = 0; k < 32; k++) {
            float av[4], bv[4];
            #pragma unroll
            for (int i = 0; i < 4; i++) av[i] = s_a[k][ty * 4 + i];
            #pragma unroll
            for (int jj = 0; jj < 4; jj++) bv[jj] = s_b[k][tx * 4 + jj];
            #pragma unroll
            for (int i = 0; i < 4; i++)
                #pragma unroll
                for (int jj = 0; jj < 4; jj++)
                    acc[i][jj] = fmaf(av[i], bv[jj], acc[i][jj]);
        }
        __syncthreads();
    }

    float4 bias = *(const float4*)(b1 + n0 + tx * 4);
    #pragma unroll
    for (int i = 0; i < 4; i++) {
        int px = m0 + ty * 4 + i;
        float4 v;
        v.x = acc[i][0] + bias.x;
        v.y = acc[i][1] + bias.y;
        v.z = acc[i][2] + bias.z;
        v.w = acc[i][3] + bias.w;
        *(float4*)(h1 + ((size_t)px << 8) + n0 + tx * 4) = v;
    }
}

// ---------------------------------------------------------------------------
// w2 [16][256][3][3] (o,c,kk) -> w2t [kk][c4][o][4ci]: for each (kk, c-group
// of 4), the 16 o-entries are contiguous float4s, so a wave's weight load
// (4 groups x 16 o) is one 256 B block (R11's [kk][o][c] layout cost 16
// cache lines per load instruction).
// ---------------------------------------------------------------------------
__global__ void k_w2t(const float* __restrict__ w2, float* __restrict__ w2t) {
    int i = blockIdx.x * 256 + threadIdx.x;
    if (i >= 16 * 256 * 9) return;
    int o  = i / 2304;
    int r  = i % 2304;         // c*9 + kk
    int c  = r / 9;
    int kk = r % 9;
    int cg = c >> 2, ci = c & 3;
    w2t[(((kk * 64 + cg) * 16 + o) << 2) + ci] = w2[i];
}

// ---------------------------------------------------------------------------
// Conv2: 3x3 pad1, 256 -> 16, FP32, numerics-free.  R12: 16-px tiles,
// grid 512, thread = (o, slot 0..7) handling pixels slot and slot+8
// (2 px/thread -> 8 independent FMA chains; R11's 1 px/thread halved ILP
// and regressed).  Weights via the [kk][c4][o] coalesced layout.
// ---------------------------------------------------------------------------
__global__ void k_conv2(const float* __restrict__ h1,
                        const float* __restrict__ w2t,
                        const float* __restrict__ b2,
                        float* __restrict__ h2) {
    __shared__ float s_in[3][18][68];
    int blk = blockIdx.x;          // 0..511
    int b   = blk >> 8;            // 256 blocks per batch
    int r   = blk & 255;
    int y   = r >> 2;
    int w0  = (r & 3) * 16;
    int tid = threadIdx.x;
    int o   = tid & 15;
    int ps  = (tid >> 4) & 7;      // slot 0..7 -> pixels ps, ps+8

    const float* hb = h1 + ((size_t)b << 20);

    float4 a0 = {0.f, 0.f, 0.f, 0.f};
    float4 a1 = {0.f, 0.f, 0.f, 0.f};

    for (int chunk = 0; chunk < 4; chunk++) {
        int c0 = chunk << 6;
        for (int i = tid; i < 3 * 18 * 16; i += 256) {   // 864 float4 stages
            int c4 = i & 15;
            int pi = (i >> 4) % 18;
            int ri = (i >> 4) / 18;
            int yy = y + ri - 1;
            int xx = w0 + pi - 1;
            float4 v = {0.f, 0.f, 0.f, 0.f};
            if ((unsigned)yy < 64u && (unsigned)xx < 64u)
                v = *(const float4*)(hb + ((size_t)((yy << 6) | xx) << 8) + c0 + (c4 << 2));
            *(float4*)&s_in[ri][pi][c4 << 2] = v;
        }
        __syncthreads();

        #pragma unroll
        for (int kk = 0; kk < 9; kk++) {
            int ky = kk / 3, kx = kk - ky * 3;
            const float* wp = w2t + (((size_t)(kk * 64 + (c0 >> 2)) * 16 + o) << 2);
            #pragma unroll 8
            for (int c4 = 0; c4 < 16; c4++) {
                float4 wv = *(const float4*)(wp + (c4 << 6));   // stride 64 floats
                float4 i0 = *(const float4*)&s_in[ky][ps + kx][c4 << 2];
                float4 i1 = *(const float4*)&s_in[ky][ps + 8 + kx][c4 << 2];
                a0.x = fmaf(wv.x, i0.x, a0.x);
                a0.y = fmaf(wv.y, i0.y, a0.y);
                a0.z = fmaf(wv.z, i0.z, a0.z);
                a0.w = fmaf(wv.w, i0.w, a0.w);
                a1.x = fmaf(wv.x, i1.x, a1.x);
                a1.y = fmaf(wv.y, i1.y, a1.y);
                a1.z = fmaf(wv.z, i1.z, a1.z);
                a1.w = fmaf(wv.w, i1.w, a1.w);
            }
        }
        __syncthreads();
    }

    size_t bp0 = ((size_t)b << 12) + (y << 6) + w0;
    h2[(bp0 + ps) * 16 + o]     = ((a0.x + a0.y) + (a0.z + a0.w)) + b2[o];
    h2[(bp0 + ps + 8) * 16 + o] = ((a1.x + a1.y) + (a1.z + a1.w)) + b2[o];
}

// ---------------------------------------------------------------------------
// Conv3: 3x3 pad1, 16 -> 3, FP32, numerics-free.  Thread per pixel.
// ---------------------------------------------------------------------------
__global__ void k_conv3(const float* __restrict__ h2,
                        const float* __restrict__ w3,
                        const float* __restrict__ b3,
                        float* __restrict__ h3) {
    int bp = blockIdx.x * 256 + threadIdx.x;
    if (bp >= BP_N) return;
    int b = bp >> 12;
    int p = bp & 4095;
    int h = p >> 6, w = p & 63;
    const float* hb = h2 + ((size_t)b << 16);   // b*4096*16

    float a0 = 0.f, a1 = 0.f, a2 = 0.f;
    #pragma unroll
    for (int kk = 0; kk < 9; kk++) {
        int ky = kk / 3, kx = kk - ky * 3;
        int y = h + ky - 1, x = w + kx - 1;
        if ((unsigned)y >= 64u || (unsigned)x >= 64u) continue;
        const float* ip = hb + (size_t)((y << 6) | x) * 16;
        #pragma unroll
        for (int c = 0; c < 16; c++) {
            float v = ip[c];
            int wi = c * 9 + kk;
            a0 = fmaf(w3[wi],       v, a0);
            a1 = fmaf(w3[144 + wi], v, a1);
            a2 = fmaf(w3[288 + wi], v, a2);
        }
    }
    h3[(size_t)bp * 3 + 0] = a0 + b3[0];
    h3[(size_t)bp * 3 + 1] = a1 + b3[1];
    h3[(size_t)bp * 3 + 2] = a2 + b3[2];
}

// ---------------------------------------------------------------------------
// Conv4 (3x3, 3 -> 2) + softmax -> (score0, score1), FP32, numerics-free.
// ---------------------------------------------------------------------------
__global__ void k_score(const float* __restrict__ h3,
                        const float* __restrict__ w4,
                        const float* __restrict__ b4,
                        float2* __restrict__ score) {
    int bp = blockIdx.x * 256 + threadIdx.x;
    if (bp >= BP_N) return;
    int b = bp >> 12;
    int p = bp & 4095;
    int h = p >> 6, w = p & 63;
    const float* hb = h3 + (size_t)b * PIX * 3;

    float l0 = 0.f, l1 = 0.f;
    #pragma unroll
    for (int kk = 0; kk < 9; kk++) {
        int ky = kk / 3, kx = kk - ky * 3;
        int y = h + ky - 1, x = w + kx - 1;
        if ((unsigned)y >= 64u || (unsigned)x >= 64u) continue;
        const float* ip = hb + (size_t)((y << 6) | x) * 3;
        #pragma unroll
        for (int c = 0; c < 3; c++) {
            float v = ip[c];
            int wi = c * 9 + kk;
            l0 = fmaf(w4[wi],      v, l0);
            l1 = fmaf(w4[27 + wi], v, l1);
        }
    }
    l0 += b4[0];
    l1 += b4[1];

    float m  = fmaxf(l0, l1);
    float e0 = expf(l0 - m);
    float e1 = expf(l1 - m);
    float s  = e0 + e1;
    score[bp] = make_float2(e0 / s, e1 / s);
}

// ---------------------------------------------------------------------------
// Blend + on-the-fly NHWC->NCHW transpose of aligned.  Verbatim from R11.
// ---------------------------------------------------------------------------
__global__ void k_blend(const float* __restrict__ feat,
                        const float* __restrict__ alignedT,
                        const float2* __restrict__ score,
                        float* __restrict__ out) {
    __shared__ float tile[32][33];
    int b  = blockIdx.z;
    int p0 = blockIdx.x * 32;
    int c0 = blockIdx.y * 32;
    int tx = threadIdx.x;     // 32
    int ty = threadIdx.y;     // 8

    const float* at = alignedT + ((size_t)b << 20);
    #pragma unroll
    for (int i = 0; i < 4; i++) {
        int p = p0 + ty + i * 8;
        tile[ty + i * 8][tx] = at[((size_t)p << 8) + c0 + tx];
    }
    __syncthreads();

    int p = p0 + tx;
    float2 s = score[(b << 12) + p];
    #pragma unroll
    for (int i = 0; i < 4; i++) {
        int c = c0 + ty + i * 8;
        size_t idx = (((size_t)(b * 256 + c)) << 12) + p;
        out[idx] = __fadd_rn(__fmul_rn(s.x, feat[idx]),
                             __fmul_rn(s.y, tile[tx][ty + i * 8]));
    }
}

// ---------------------------------------------------------------------------
extern "C" void kernel_launch(void* const* d_in, const int* in_sizes, int n_in,
                              void* d_out, int out_size, void* d_ws, size_t ws_size,
                              hipStream_t stream) {
    const float* feat     = (const float*)d_in[0];
    const float* feat_ref = (const float*)d_in[1];
    const float* w1 = (const float*)d_in[2];
    const float* b1 = (const float*)d_in[3];
    const float* w2 = (const float*)d_in[4];
    const float* b2 = (const float*)d_in[5];
    const float* w3 = (const float*)d_in[6];
    const float* b3 = (const float*)d_in[7];
    const float* w4 = (const float*)d_in[8];
    const float* b4 = (const float*)d_in[9];
    float* out = (float*)d_out;

    const size_t NCP = (size_t)BATCH * CCH * PIX;   // 2,097,152
    char* wsb = (char*)d_ws;
    float*  featT    = (float*)wsb;   wsb += NCP * 4;               // 8 MB
    float*  refT     = (float*)wsb;   wsb += NCP * 4;               // 8 MB
    float*  alignedT = (float*)wsb;   wsb += NCP * 4;               // 8 MB
    float*  h1       = (float*)wsb;   wsb += NCP * 4;               // 8 MB
    float*  h2       = (float*)wsb;   wsb += (size_t)BP_N * 16 * 4;
    float*  h3       = (float*)wsb;   wsb += (size_t)BP_N * 3 * 4;
    float2* sc       = (float2*)wsb;  wsb += (size_t)BP_N * 8;
    float*  w2t      = (float*)wsb;   wsb += (size_t)16 * 256 * 9 * 4;

    dim3 tb(32, 8, 1);
    dim3 tg(PIX / 32, CCH / 32, BATCH);
    k_transpose<<<tg, tb, 0, stream>>>(feat, featT);
    k_transpose<<<tg, tb, 0, stream>>>(feat_ref, refT);
    k_w2t<<<144, 256, 0, stream>>>(w2, w2t);

    k_corr_assemble<<<BP_N, 256, 0, stream>>>(featT, refT, alignedT);
    k_conv1<<<dim3(BP_N / 64, 256 / 64, 1), 256, 0, stream>>>(featT, alignedT, w1, b1, h1);
    k_conv2<<<BP_N / 16, 256, 0, stream>>>(h1, w2t, b2, h2);
    k_conv3<<<BP_N / 256, 256, 0, stream>>>(h2, w3, b3, h3);
    k_score<<<BP_N / 256, 256, 0, stream>>>(h3, w4, b4, sc);
    k_blend<<<tg, tb, 0, stream>>>(feat, alignedT, sc, out);
}

// Round 13
// 269.764 us; speedup vs baseline: 1.5784x; 1.2470x over previous
//
#include <hip/hip_runtime.h>
#include <hip/hip_bf16.h>
#include <math.h>

// Problem constants (B=2, C=256, H=W=64, D=4, K=9, K2=81)
#define BATCH 2
#define CCH   256
#define HH    64
#define WW    64
#define PIX   (HH*WW)          // 4096
#define K2    81
#define BP_N  (BATCH*PIX)      // 8192

// ---------------------------------------------------------------------------
// NCHW -> NHWC tiled transpose (per batch).  in: [B][C][P]  out: [B][P][C]
// ---------------------------------------------------------------------------
__global__ void k_transpose(const float* __restrict__ in, float* __restrict__ out) {
    __shared__ float tile[32][33];
    int b  = blockIdx.z;
    int p0 = blockIdx.x * 32;
    int c0 = blockIdx.y * 32;
    int tx = threadIdx.x;     // 32
    int ty = threadIdx.y;     // 8
    const float* ib = in  + (size_t)b * CCH * PIX;
    float*       ob = out + (size_t)b * CCH * PIX;
    #pragma unroll
    for (int i = 0; i < 4; i++) {
        int c = c0 + ty + i * 8;
        int p = p0 + tx;
        tile[ty + i * 8][tx] = ib[(size_t)c * PIX + p];
    }
    __syncthreads();
    #pragma unroll
    for (int i = 0; i < 4; i++) {
        int p = p0 + ty + i * 8;
        int c = c0 + tx;
        ob[(size_t)p * CCH + c] = tile[tx][ty + i * 8];
    }
}

// ---------------------------------------------------------------------------
// Correlation + sum-normalize + assemble — BIT-EXACT recipe (passed R7-R12,
// absmax 16384/19988).  DO NOT CHANGE ANY ROUNDING.  Verbatim from R12.
// ---------------------------------------------------------------------------
__global__ void k_corr_assemble(const float* __restrict__ featT,
                                const float* __restrict__ refT,
                                float* __restrict__ alignedT) {
    int bp = blockIdx.x;               // 0..8191
    int b  = bp >> 12;
    int p  = bp & 4095;
    int h  = p >> 6, w = p & 63;
    int tid = threadIdx.x;             // 0..255

    __shared__ float s_feat[256];
    __shared__ float s_aff[K2];
    __shared__ float s_affn[K2];
    __shared__ int   s_pix[K2];
    __shared__ float s_den;

    s_feat[tid] = featT[((size_t)bp << 8) + tid];
    if (tid < K2) {
        int dy = tid / 9, dx = tid - dy * 9;
        int y = h + dy - 4, x = w + dx - 4;
        s_pix[tid] = ((unsigned)y < 64u && (unsigned)x < 64u) ? ((y << 6) | x) : -1;
    }
    __syncthreads();

    const float* rb = refT + ((size_t)b << 20);   // b*4096*256

    // Phase 1: lane-parallel strided partials + butterfly combine.
    int hw = tid >> 5;        // 0..7
    int j  = tid & 31;        // 0..31
    for (int it = 0; it < 11; it++) {
        int k = it * 8 + hw;
        float partial = 0.f;
        int pix = (k < K2) ? s_pix[k] : -1;
        if (pix >= 0) {
            const float* rp = rb + ((size_t)pix << 8);
            #pragma unroll
            for (int t = 0; t < 8; t++) {
                int c = 32 * t + j;
                partial = fmaf(s_feat[c], rp[c], partial);
            }
        }
        partial = __fadd_rn(partial, __shfl_xor(partial, 8));
        partial = __fadd_rn(partial, __shfl_xor(partial, 16));
        partial = __fadd_rn(partial, __shfl_xor(partial, 4));
        partial = __fadd_rn(partial, __shfl_xor(partial, 2));
        partial = __fadd_rn(partial, __shfl_xor(partial, 1));
        if (j == 0 && k < K2) s_aff[k] = partial;
    }
    __syncthreads();

    // Phase 2: s = sequential ascending-k fp32 add chain; den = s + 1e-7f
    if (tid == 0) {
        float s = 0.f;
        for (int k = 0; k < K2; k++) s = __fadd_rn(s, s_aff[k]);
        s_den = __fadd_rn(s, 1e-7f);
    }
    __syncthreads();
    if (tid < K2) s_affn[tid] = __fdiv_rn(s_aff[tid], s_den);
    __syncthreads();

    // Phase 3: aligned[c] = sequential ascending-k FMA chain (coalesced)
    int c = tid;
    float acc = 0.f;
    for (int k = 0; k < K2; k++) {
        int pix = s_pix[k];
        if (pix >= 0)
            acc = fmaf(s_affn[k], rb[((size_t)pix << 8) + c], acc);
    }
    alignedT[((size_t)bp << 8) + c] = acc;
}

// ---------------------------------------------------------------------------
// w1 [256][512] (o,c) -> w1t [512][256] (c,o): lets conv1 stage B coalesced.
// ---------------------------------------------------------------------------
__global__ void k_w1t(const float* __restrict__ w1, float* __restrict__ w1t) {
    __shared__ float tile[32][33];
    int c0 = blockIdx.x * 32;
    int o0 = blockIdx.y * 32;
    int tx = threadIdx.x;     // 32
    int ty = threadIdx.y;     // 8
    #pragma unroll
    for (int i = 0; i < 4; i++)
        tile[ty + i * 8][tx] = w1[(size_t)(o0 + ty + i * 8) * 512 + c0 + tx];
    __syncthreads();
    #pragma unroll
    for (int i = 0; i < 4; i++)
        w1t[(size_t)(c0 + ty + i * 8) * 256 + o0 + tx] = tile[tx][ty + i * 8];
}

// ---------------------------------------------------------------------------
// Conv1: 1x1, 512 -> 256, FP32 GEMM (numerics-free).  R13: both LDS tiles
// padded to stride 68 (272 B = 17x16 -> every [k][quad*4] is 16B-aligned) so
// the inner loop is 2 ds_read_b128 + 16 FMA per k (R12 issued 8 scalar
// ds_read_b32 -> LDS-issue-bound, 6.3M bank-conflict cycles).  B staged from
// the pre-transposed w1t (coalesced).  acc structure (4x4 fmaf) unchanged.
// ---------------------------------------------------------------------------
__global__ void k_conv1(const float* __restrict__ featT,
                        const float* __restrict__ alignedT,
                        const float* __restrict__ w1t,
                        const float* __restrict__ b1,
                        float* __restrict__ h1) {
    __shared__ float s_a[32][68];     // [k][px]
    __shared__ float s_b[32][68];     // [k][o]
    int m0  = blockIdx.x * 64;        // pixel base
    int n0  = blockIdx.y * 64;        // out-channel base
    int tid = threadIdx.x;
    int tx  = tid & 15;               // o quad
    int ty  = tid >> 4;               // px quad

    float acc[4][4] = {{0.f}};

    for (int kc = 0; kc < 16; kc++) {
        int c0 = kc * 32;
        const float* asrc;
        int coff;
        if (c0 < 256) { asrc = featT;    coff = c0; }
        else          { asrc = alignedT; coff = c0 - 256; }

        // A: 64 px x 32 c.  float4 global loads (coalesced), scalar LDS
        // scatter (4-way alias on 8 instr/chunk — negligible).
        #pragma unroll
        for (int i = tid; i < 512; i += 256) {
            int cq = i & 7, px = i >> 3;
            float4 v = *(const float4*)(asrc + ((size_t)(m0 + px) << 8) + coff + (cq << 2));
            s_a[cq * 4 + 0][px] = v.x;
            s_a[cq * 4 + 1][px] = v.y;
            s_a[cq * 4 + 2][px] = v.z;
            s_a[cq * 4 + 3][px] = v.w;
        }
        // B: 32 c x 64 o from w1t[c][o].  float4 both sides.
        #pragma unroll
        for (int i = tid; i < 512; i += 256) {
            int oq = i & 15, cc = i >> 4;
            float4 v = *(const float4*)(w1t + (size_t)(c0 + cc) * 256 + n0 + (oq << 2));
            *(float4*)&s_b[cc][oq << 2] = v;
        }
        __syncthreads();

        #pragma unroll 8
        for (int k = 0; k < 32; k++) {
            float4 av = *(const float4*)&s_a[k][ty << 2];
            float4 bv = *(const float4*)&s_b[k][tx << 2];
            acc[0][0] = fmaf(av.x, bv.x, acc[0][0]);
            acc[0][1] = fmaf(av.x, bv.y, acc[0][1]);
            acc[0][2] = fmaf(av.x, bv.z, acc[0][2]);
            acc[0][3] = fmaf(av.x, bv.w, acc[0][3]);
            acc[1][0] = fmaf(av.y, bv.x, acc[1][0]);
            acc[1][1] = fmaf(av.y, bv.y, acc[1][1]);
            acc[1][2] = fmaf(av.y, bv.z, acc[1][2]);
            acc[1][3] = fmaf(av.y, bv.w, acc[1][3]);
            acc[2][0] = fmaf(av.z, bv.x, acc[2][0]);
            acc[2][1] = fmaf(av.z, bv.y, acc[2][1]);
            acc[2][2] = fmaf(av.z, bv.z, acc[2][2]);
            acc[2][3] = fmaf(av.z, bv.w, acc[2][3]);
            acc[3][0] = fmaf(av.w, bv.x, acc[3][0]);
            acc[3][1] = fmaf(av.w, bv.y, acc[3][1]);
            acc[3][2] = fmaf(av.w, bv.z, acc[3][2]);
            acc[3][3] = fmaf(av.w, bv.w, acc[3][3]);
        }
        __syncthreads();
    }

    float4 bias = *(const float4*)(b1 + n0 + tx * 4);
    #pragma unroll
    for (int i = 0; i < 4; i++) {
        int px = m0 + ty * 4 + i;
        float4 v;
        v.x = acc[i][0] + bias.x;
        v.y = acc[i][1] + bias.y;
        v.z = acc[i][2] + bias.z;
        v.w = acc[i][3] + bias.w;
        *(float4*)(h1 + ((size_t)px << 8) + n0 + tx * 4) = v;
    }
}

// ---------------------------------------------------------------------------
// w2 [16][256][3][3] (o,c,kk) -> w2t [kk][c4][o][4ci]  (R12 layout)
// ---------------------------------------------------------------------------
__global__ void k_w2t(const float* __restrict__ w2, float* __restrict__ w2t) {
    int i = blockIdx.x * 256 + threadIdx.x;
    if (i >= 16 * 256 * 9) return;
    int o  = i / 2304;
    int r  = i % 2304;         // c*9 + kk
    int c  = r / 9;
    int kk = r % 9;
    int cg = c >> 2, ci = c & 3;
    w2t[(((kk * 64 + cg) * 16 + o) << 2) + ci] = w2[i];
}

// ---------------------------------------------------------------------------
// Conv2: 3x3 pad1, 256 -> 16, FP32, numerics-free.  Verbatim from R12.
// ---------------------------------------------------------------------------
__global__ void k_conv2(const float* __restrict__ h1,
                        const float* __restrict__ w2t,
                        const float* __restrict__ b2,
                        float* __restrict__ h2) {
    __shared__ float s_in[3][18][68];
    int blk = blockIdx.x;          // 0..511
    int b   = blk >> 8;            // 256 blocks per batch
    int r   = blk & 255;
    int y   = r >> 2;
    int w0  = (r & 3) * 16;
    int tid = threadIdx.x;
    int o   = tid & 15;
    int ps  = (tid >> 4) & 7;      // slot 0..7 -> pixels ps, ps+8

    const float* hb = h1 + ((size_t)b << 20);

    float4 a0 = {0.f, 0.f, 0.f, 0.f};
    float4 a1 = {0.f, 0.f, 0.f, 0.f};

    for (int chunk = 0; chunk < 4; chunk++) {
        int c0 = chunk << 6;
        for (int i = tid; i < 3 * 18 * 16; i += 256) {
            int c4 = i & 15;
            int pi = (i >> 4) % 18;
            int ri = (i >> 4) / 18;
            int yy = y + ri - 1;
            int xx = w0 + pi - 1;
            float4 v = {0.f, 0.f, 0.f, 0.f};
            if ((unsigned)yy < 64u && (unsigned)xx < 64u)
                v = *(const float4*)(hb + ((size_t)((yy << 6) | xx) << 8) + c0 + (c4 << 2));
            *(float4*)&s_in[ri][pi][c4 << 2] = v;
        }
        __syncthreads();

        #pragma unroll
        for (int kk = 0; kk < 9; kk++) {
            int ky = kk / 3, kx = kk - ky * 3;
            const float* wp = w2t + (((size_t)(kk * 64 + (c0 >> 2)) * 16 + o) << 2);
            #pragma unroll 8
            for (int c4 = 0; c4 < 16; c4++) {
                float4 wv = *(const float4*)(wp + (c4 << 6));
                float4 i0 = *(const float4*)&s_in[ky][ps + kx][c4 << 2];
                float4 i1 = *(const float4*)&s_in[ky][ps + 8 + kx][c4 << 2];
                a0.x = fmaf(wv.x, i0.x, a0.x);
                a0.y = fmaf(wv.y, i0.y, a0.y);
                a0.z = fmaf(wv.z, i0.z, a0.z);
                a0.w = fmaf(wv.w, i0.w, a0.w);
                a1.x = fmaf(wv.x, i1.x, a1.x);
                a1.y = fmaf(wv.y, i1.y, a1.y);
                a1.z = fmaf(wv.z, i1.z, a1.z);
                a1.w = fmaf(wv.w, i1.w, a1.w);
            }
        }
        __syncthreads();
    }

    size_t bp0 = ((size_t)b << 12) + (y << 6) + w0;
    h2[(bp0 + ps) * 16 + o]     = ((a0.x + a0.y) + (a0.z + a0.w)) + b2[o];
    h2[(bp0 + ps + 8) * 16 + o] = ((a1.x + a1.y) + (a1.z + a1.w)) + b2[o];
}

// ---------------------------------------------------------------------------
// Conv3: 3x3 pad1, 16 -> 3, FP32, numerics-free.  Thread per pixel.
// ---------------------------------------------------------------------------
__global__ void k_conv3(const float* __restrict__ h2,
                        const float* __restrict__ w3,
                        const float* __restrict__ b3,
                        float* __restrict__ h3) {
    int bp = blockIdx.x * 256 + threadIdx.x;
    if (bp >= BP_N) return;
    int b = bp >> 12;
    int p = bp & 4095;
    int h = p >> 6, w = p & 63;
    const float* hb = h2 + ((size_t)b << 16);   // b*4096*16

    float a0 = 0.f, a1 = 0.f, a2 = 0.f;
    #pragma unroll
    for (int kk = 0; kk < 9; kk++) {
        int ky = kk / 3, kx = kk - ky * 3;
        int y = h + ky - 1, x = w + kx - 1;
        if ((unsigned)y >= 64u || (unsigned)x >= 64u) continue;
        const float* ip = hb + (size_t)((y << 6) | x) * 16;
        #pragma unroll
        for (int c = 0; c < 16; c++) {
            float v = ip[c];
            int wi = c * 9 + kk;
            a0 = fmaf(w3[wi],       v, a0);
            a1 = fmaf(w3[144 + wi], v, a1);
            a2 = fmaf(w3[288 + wi], v, a2);
        }
    }
    h3[(size_t)bp * 3 + 0] = a0 + b3[0];
    h3[(size_t)bp * 3 + 1] = a1 + b3[1];
    h3[(size_t)bp * 3 + 2] = a2 + b3[2];
}

// ---------------------------------------------------------------------------
// Conv4 (3x3, 3 -> 2) + softmax -> (score0, score1), FP32, numerics-free.
// ---------------------------------------------------------------------------
__global__ void k_score(const float* __restrict__ h3,
                        const float* __restrict__ w4,
                        const float* __restrict__ b4,
                        float2* __restrict__ score) {
    int bp = blockIdx.x * 256 + threadIdx.x;
    if (bp >= BP_N) return;
    int b = bp >> 12;
    int p = bp & 4095;
    int h = p >> 6, w = p & 63;
    const float* hb = h3 + (size_t)b * PIX * 3;

    float l0 = 0.f, l1 = 0.f;
    #pragma unroll
    for (int kk = 0; kk < 9; kk++) {
        int ky = kk / 3, kx = kk - ky * 3;
        int y = h + ky - 1, x = w + kx - 1;
        if ((unsigned)y >= 64u || (unsigned)x >= 64u) continue;
        const float* ip = hb + (size_t)((y << 6) | x) * 3;
        #pragma unroll
        for (int c = 0; c < 3; c++) {
            float v = ip[c];
            int wi = c * 9 + kk;
            l0 = fmaf(w4[wi],      v, l0);
            l1 = fmaf(w4[27 + wi], v, l1);
        }
    }
    l0 += b4[0];
    l1 += b4[1];

    float m  = fmaxf(l0, l1);
    float e0 = expf(l0 - m);
    float e1 = expf(l1 - m);
    float s  = e0 + e1;
    score[bp] = make_float2(e0 / s, e1 / s);
}

// ---------------------------------------------------------------------------
// Blend + on-the-fly NHWC->NCHW transpose of aligned.  Verbatim from R11.
// ---------------------------------------------------------------------------
__global__ void k_blend(const float* __restrict__ feat,
                        const float* __restrict__ alignedT,
                        const float2* __restrict__ score,
                        float* __restrict__ out) {
    __shared__ float tile[32][33];
    int b  = blockIdx.z;
    int p0 = blockIdx.x * 32;
    int c0 = blockIdx.y * 32;
    int tx = threadIdx.x;     // 32
    int ty = threadIdx.y;     // 8

    const float* at = alignedT + ((size_t)b << 20);
    #pragma unroll
    for (int i = 0; i < 4; i++) {
        int p = p0 + ty + i * 8;
        tile[ty + i * 8][tx] = at[((size_t)p << 8) + c0 + tx];
    }
    __syncthreads();

    int p = p0 + tx;
    float2 s = score[(b << 12) + p];
    #pragma unroll
    for (int i = 0; i < 4; i++) {
        int c = c0 + ty + i * 8;
        size_t idx = (((size_t)(b * 256 + c)) << 12) + p;
        out[idx] = __fadd_rn(__fmul_rn(s.x, feat[idx]),
                             __fmul_rn(s.y, tile[tx][ty + i * 8]));
    }
}

// ---------------------------------------------------------------------------
extern "C" void kernel_launch(void* const* d_in, const int* in_sizes, int n_in,
                              void* d_out, int out_size, void* d_ws, size_t ws_size,
                              hipStream_t stream) {
    const float* feat     = (const float*)d_in[0];
    const float* feat_ref = (const float*)d_in[1];
    const float* w1 = (const float*)d_in[2];
    const float* b1 = (const float*)d_in[3];
    const float* w2 = (const float*)d_in[4];
    const float* b2 = (const float*)d_in[5];
    const float* w3 = (const float*)d_in[6];
    const float* b3 = (const float*)d_in[7];
    const float* w4 = (const float*)d_in[8];
    const float* b4 = (const float*)d_in[9];
    float* out = (float*)d_out;

    const size_t NCP = (size_t)BATCH * CCH * PIX;   // 2,097,152
    char* wsb = (char*)d_ws;
    float*  featT    = (float*)wsb;   wsb += NCP * 4;               // 8 MB
    float*  refT     = (float*)wsb;   wsb += NCP * 4;               // 8 MB
    float*  alignedT = (float*)wsb;   wsb += NCP * 4;               // 8 MB
    float*  h1       = (float*)wsb;   wsb += NCP * 4;               // 8 MB
    float*  h2       = (float*)wsb;   wsb += (size_t)BP_N * 16 * 4;
    float*  h3       = (float*)wsb;   wsb += (size_t)BP_N * 3 * 4;
    float2* sc       = (float2*)wsb;  wsb += (size_t)BP_N * 8;
    float*  w2t      = (float*)wsb;   wsb += (size_t)16 * 256 * 9 * 4;
    float*  w1t      = (float*)wsb;   wsb += (size_t)512 * 256 * 4;

    dim3 tb(32, 8, 1);
    dim3 tg(PIX / 32, CCH / 32, BATCH);
    k_transpose<<<tg, tb, 0, stream>>>(feat, featT);
    k_transpose<<<tg, tb, 0, stream>>>(feat_ref, refT);
    k_w2t<<<144, 256, 0, stream>>>(w2, w2t);
    k_w1t<<<dim3(16, 8, 1), tb, 0, stream>>>(w1, w1t);

    k_corr_assemble<<<BP_N, 256, 0, stream>>>(featT, refT, alignedT);
    k_conv1<<<dim3(BP_N / 64, 256 / 64, 1), 256, 0, stream>>>(featT, alignedT, w1t, b1, h1);
    k_conv2<<<BP_N / 16, 256, 0, stream>>>(h1, w2t, b2, h2);
    k_conv3<<<BP_N / 256, 256, 0, stream>>>(h2, w3, b3, h3);
    k_score<<<BP_N / 256, 256, 0, stream>>>(h3, w4, b4, sc);
    k_blend<<<tg, tb, 0, stream>>>(feat, alignedT, sc, out);
}

// Round 14
// 263.867 us; speedup vs baseline: 1.6137x; 1.0223x over previous
//
#include <hip/hip_runtime.h>
#include <hip/hip_bf16.h>
#include <math.h>

// Problem constants (B=2, C=256, H=W=64, D=4, K=9, K2=81)
#define BATCH 2
#define CCH   256
#define HH    64
#define WW    64
#define PIX   (HH*WW)          // 4096
#define K2    81
#define BP_N  (BATCH*PIX)      // 8192

// ---------------------------------------------------------------------------
// NCHW -> NHWC tiled transpose (per batch).  in: [B][C][P]  out: [B][P][C]
// ---------------------------------------------------------------------------
__global__ void k_transpose(const float* __restrict__ in, float* __restrict__ out) {
    __shared__ float tile[32][33];
    int b  = blockIdx.z;
    int p0 = blockIdx.x * 32;
    int c0 = blockIdx.y * 32;
    int tx = threadIdx.x;     // 32
    int ty = threadIdx.y;     // 8
    const float* ib = in  + (size_t)b * CCH * PIX;
    float*       ob = out + (size_t)b * CCH * PIX;
    #pragma unroll
    for (int i = 0; i < 4; i++) {
        int c = c0 + ty + i * 8;
        int p = p0 + tx;
        tile[ty + i * 8][tx] = ib[(size_t)c * PIX + p];
    }
    __syncthreads();
    #pragma unroll
    for (int i = 0; i < 4; i++) {
        int p = p0 + ty + i * 8;
        int c = c0 + tx;
        ob[(size_t)p * CCH + c] = tile[tx][ty + i * 8];
    }
}

// ---------------------------------------------------------------------------
// Correlation + sum-normalize + assemble — BIT-EXACT recipe (passed R7-R13,
// absmax 16384/19988).  DO NOT CHANGE ANY ROUNDING.
//
// R14: XCD-aware block swizzle ONLY.  R13 measured corr at 13.6 TB/s read BW
// (1.33 GB / 98 µs) = the L3 ceiling: round-robin block->XCD dispatch makes
// every 4 MB per-XCD L2 thrash over the whole 8 MB refT.  Remapping
// bp = ((blk&7)<<10)|(blk>>3) gives each XCD a contiguous 16-row band whose
// ref window (24 rows ~ 1.5 MB) fits its L2; phase 3 re-reads hit warm L2.
// Pure relabeling — per-pixel computation bit-identical.
// ---------------------------------------------------------------------------
__global__ void k_corr_assemble(const float* __restrict__ featT,
                                const float* __restrict__ refT,
                                float* __restrict__ alignedT) {
    int blk = blockIdx.x;
    int bp  = ((blk & 7) << 10) | (blk >> 3);   // XCD-contiguous pixel bands
    int b  = bp >> 12;
    int p  = bp & 4095;
    int h  = p >> 6, w = p & 63;
    int tid = threadIdx.x;             // 0..255

    __shared__ float s_feat[256];
    __shared__ float s_aff[K2];
    __shared__ float s_affn[K2];
    __shared__ int   s_pix[K2];
    __shared__ float s_den;

    s_feat[tid] = featT[((size_t)bp << 8) + tid];
    if (tid < K2) {
        int dy = tid / 9, dx = tid - dy * 9;
        int y = h + dy - 4, x = w + dx - 4;
        s_pix[tid] = ((unsigned)y < 64u && (unsigned)x < 64u) ? ((y << 6) | x) : -1;
    }
    __syncthreads();

    const float* rb = refT + ((size_t)b << 20);   // b*4096*256

    // Phase 1: lane-parallel strided partials + butterfly combine.
    int hw = tid >> 5;        // 0..7
    int j  = tid & 31;        // 0..31
    for (int it = 0; it < 11; it++) {
        int k = it * 8 + hw;
        float partial = 0.f;
        int pix = (k < K2) ? s_pix[k] : -1;
        if (pix >= 0) {
            const float* rp = rb + ((size_t)pix << 8);
            #pragma unroll
            for (int t = 0; t < 8; t++) {
                int c = 32 * t + j;
                partial = fmaf(s_feat[c], rp[c], partial);
            }
        }
        partial = __fadd_rn(partial, __shfl_xor(partial, 8));
        partial = __fadd_rn(partial, __shfl_xor(partial, 16));
        partial = __fadd_rn(partial, __shfl_xor(partial, 4));
        partial = __fadd_rn(partial, __shfl_xor(partial, 2));
        partial = __fadd_rn(partial, __shfl_xor(partial, 1));
        if (j == 0 && k < K2) s_aff[k] = partial;
    }
    __syncthreads();

    // Phase 2: s = sequential ascending-k fp32 add chain; den = s + 1e-7f
    if (tid == 0) {
        float s = 0.f;
        for (int k = 0; k < K2; k++) s = __fadd_rn(s, s_aff[k]);
        s_den = __fadd_rn(s, 1e-7f);
    }
    __syncthreads();
    if (tid < K2) s_affn[tid] = __fdiv_rn(s_aff[tid], s_den);
    __syncthreads();

    // Phase 3: aligned[c] = sequential ascending-k FMA chain (coalesced)
    int c = tid;
    float acc = 0.f;
    for (int k = 0; k < K2; k++) {
        int pix = s_pix[k];
        if (pix >= 0)
            acc = fmaf(s_affn[k], rb[((size_t)pix << 8) + c], acc);
    }
    alignedT[((size_t)bp << 8) + c] = acc;
}

// ---------------------------------------------------------------------------
// w1 [256][512] (o,c) -> w1t [512][256] (c,o): lets conv1 stage B coalesced.
// ---------------------------------------------------------------------------
__global__ void k_w1t(const float* __restrict__ w1, float* __restrict__ w1t) {
    __shared__ float tile[32][33];
    int c0 = blockIdx.x * 32;
    int o0 = blockIdx.y * 32;
    int tx = threadIdx.x;     // 32
    int ty = threadIdx.y;     // 8
    #pragma unroll
    for (int i = 0; i < 4; i++)
        tile[ty + i * 8][tx] = w1[(size_t)(o0 + ty + i * 8) * 512 + c0 + tx];
    __syncthreads();
    #pragma unroll
    for (int i = 0; i < 4; i++)
        w1t[(size_t)(c0 + ty + i * 8) * 256 + o0 + tx] = tile[tx][ty + i * 8];
}

// ---------------------------------------------------------------------------
// Conv1: 1x1, 512 -> 256, FP32 GEMM (numerics-free).  Verbatim from R13.
// ---------------------------------------------------------------------------
__global__ void k_conv1(const float* __restrict__ featT,
                        const float* __restrict__ alignedT,
                        const float* __restrict__ w1t,
                        const float* __restrict__ b1,
                        float* __restrict__ h1) {
    __shared__ float s_a[32][68];     // [k][px]
    __shared__ float s_b[32][68];     // [k][o]
    int m0  = blockIdx.x * 64;        // pixel base
    int n0  = blockIdx.y * 64;        // out-channel base
    int tid = threadIdx.x;
    int tx  = tid & 15;               // o quad
    int ty  = tid >> 4;               // px quad

    float acc[4][4] = {{0.f}};

    for (int kc = 0; kc < 16; kc++) {
        int c0 = kc * 32;
        const float* asrc;
        int coff;
        if (c0 < 256) { asrc = featT;    coff = c0; }
        else          { asrc = alignedT; coff = c0 - 256; }

        #pragma unroll
        for (int i = tid; i < 512; i += 256) {
            int cq = i & 7, px = i >> 3;
            float4 v = *(const float4*)(asrc + ((size_t)(m0 + px) << 8) + coff + (cq << 2));
            s_a[cq * 4 + 0][px] = v.x;
            s_a[cq * 4 + 1][px] = v.y;
            s_a[cq * 4 + 2][px] = v.z;
            s_a[cq * 4 + 3][px] = v.w;
        }
        #pragma unroll
        for (int i = tid; i < 512; i += 256) {
            int oq = i & 15, cc = i >> 4;
            float4 v = *(const float4*)(w1t + (size_t)(c0 + cc) * 256 + n0 + (oq << 2));
            *(float4*)&s_b[cc][oq << 2] = v;
        }
        __syncthreads();

        #pragma unroll 8
        for (int k = 0; k < 32; k++) {
            float4 av = *(const float4*)&s_a[k][ty << 2];
            float4 bv = *(const float4*)&s_b[k][tx << 2];
            acc[0][0] = fmaf(av.x, bv.x, acc[0][0]);
            acc[0][1] = fmaf(av.x, bv.y, acc[0][1]);
            acc[0][2] = fmaf(av.x, bv.z, acc[0][2]);
            acc[0][3] = fmaf(av.x, bv.w, acc[0][3]);
            acc[1][0] = fmaf(av.y, bv.x, acc[1][0]);
            acc[1][1] = fmaf(av.y, bv.y, acc[1][1]);
            acc[1][2] = fmaf(av.y, bv.z, acc[1][2]);
            acc[1][3] = fmaf(av.y, bv.w, acc[1][3]);
            acc[2][0] = fmaf(av.z, bv.x, acc[2][0]);
            acc[2][1] = fmaf(av.z, bv.y, acc[2][1]);
            acc[2][2] = fmaf(av.z, bv.z, acc[2][2]);
            acc[2][3] = fmaf(av.z, bv.w, acc[2][3]);
            acc[3][0] = fmaf(av.w, bv.x, acc[3][0]);
            acc[3][1] = fmaf(av.w, bv.y, acc[3][1]);
            acc[3][2] = fmaf(av.w, bv.z, acc[3][2]);
            acc[3][3] = fmaf(av.w, bv.w, acc[3][3]);
        }
        __syncthreads();
    }

    float4 bias = *(const float4*)(b1 + n0 + tx * 4);
    #pragma unroll
    for (int i = 0; i < 4; i++) {
        int px = m0 + ty * 4 + i;
        float4 v;
        v.x = acc[i][0] + bias.x;
        v.y = acc[i][1] + bias.y;
        v.z = acc[i][2] + bias.z;
        v.w = acc[i][3] + bias.w;
        *(float4*)(h1 + ((size_t)px << 8) + n0 + tx * 4) = v;
    }
}

// ---------------------------------------------------------------------------
// w2 [16][256][3][3] (o,c,kk) -> w2t [kk][c4][o][4ci]  (R12 layout)
// ---------------------------------------------------------------------------
__global__ void k_w2t(const float* __restrict__ w2, float* __restrict__ w2t) {
    int i = blockIdx.x * 256 + threadIdx.x;
    if (i >= 16 * 256 * 9) return;
    int o  = i / 2304;
    int r  = i % 2304;         // c*9 + kk
    int c  = r / 9;
    int kk = r % 9;
    int cg = c >> 2, ci = c & 3;
    w2t[(((kk * 64 + cg) * 16 + o) << 2) + ci] = w2[i];
}

// ---------------------------------------------------------------------------
// Conv2: 3x3 pad1, 256 -> 16, FP32, numerics-free.  Verbatim from R12.
// ---------------------------------------------------------------------------
__global__ void k_conv2(const float* __restrict__ h1,
                        const float* __restrict__ w2t,
                        const float* __restrict__ b2,
                        float* __restrict__ h2) {
    __shared__ float s_in[3][18][68];
    int blk = blockIdx.x;          // 0..511
    int b   = blk >> 8;            // 256 blocks per batch
    int r   = blk & 255;
    int y   = r >> 2;
    int w0  = (r & 3) * 16;
    int tid = threadIdx.x;
    int o   = tid & 15;
    int ps  = (tid >> 4) & 7;      // slot 0..7 -> pixels ps, ps+8

    const float* hb = h1 + ((size_t)b << 20);

    float4 a0 = {0.f, 0.f, 0.f, 0.f};
    float4 a1 = {0.f, 0.f, 0.f, 0.f};

    for (int chunk = 0; chunk < 4; chunk++) {
        int c0 = chunk << 6;
        for (int i = tid; i < 3 * 18 * 16; i += 256) {
            int c4 = i & 15;
            int pi = (i >> 4) % 18;
            int ri = (i >> 4) / 18;
            int yy = y + ri - 1;
            int xx = w0 + pi - 1;
            float4 v = {0.f, 0.f, 0.f, 0.f};
            if ((unsigned)yy < 64u && (unsigned)xx < 64u)
                v = *(const float4*)(hb + ((size_t)((yy << 6) | xx) << 8) + c0 + (c4 << 2));
            *(float4*)&s_in[ri][pi][c4 << 2] = v;
        }
        __syncthreads();

        #pragma unroll
        for (int kk = 0; kk < 9; kk++) {
            int ky = kk / 3, kx = kk - ky * 3;
            const float* wp = w2t + (((size_t)(kk * 64 + (c0 >> 2)) * 16 + o) << 2);
            #pragma unroll 8
            for (int c4 = 0; c4 < 16; c4++) {
                float4 wv = *(const float4*)(wp + (c4 << 6));
                float4 i0 = *(const float4*)&s_in[ky][ps + kx][c4 << 2];
                float4 i1 = *(const float4*)&s_in[ky][ps + 8 + kx][c4 << 2];
                a0.x = fmaf(wv.x, i0.x, a0.x);
                a0.y = fmaf(wv.y, i0.y, a0.y);
                a0.z = fmaf(wv.z, i0.z, a0.z);
                a0.w = fmaf(wv.w, i0.w, a0.w);
                a1.x = fmaf(wv.x, i1.x, a1.x);
                a1.y = fmaf(wv.y, i1.y, a1.y);
                a1.z = fmaf(wv.z, i1.z, a1.z);
                a1.w = fmaf(wv.w, i1.w, a1.w);
            }
        }
        __syncthreads();
    }

    size_t bp0 = ((size_t)b << 12) + (y << 6) + w0;
    h2[(bp0 + ps) * 16 + o]     = ((a0.x + a0.y) + (a0.z + a0.w)) + b2[o];
    h2[(bp0 + ps + 8) * 16 + o] = ((a1.x + a1.y) + (a1.z + a1.w)) + b2[o];
}

// ---------------------------------------------------------------------------
// Conv3: 3x3 pad1, 16 -> 3, FP32, numerics-free.  Thread per pixel.
// ---------------------------------------------------------------------------
__global__ void k_conv3(const float* __restrict__ h2,
                        const float* __restrict__ w3,
                        const float* __restrict__ b3,
                        float* __restrict__ h3) {
    int bp = blockIdx.x * 256 + threadIdx.x;
    if (bp >= BP_N) return;
    int b = bp >> 12;
    int p = bp & 4095;
    int h = p >> 6, w = p & 63;
    const float* hb = h2 + ((size_t)b << 16);   // b*4096*16

    float a0 = 0.f, a1 = 0.f, a2 = 0.f;
    #pragma unroll
    for (int kk = 0; kk < 9; kk++) {
        int ky = kk / 3, kx = kk - ky * 3;
        int y = h + ky - 1, x = w + kx - 1;
        if ((unsigned)y >= 64u || (unsigned)x >= 64u) continue;
        const float* ip = hb + (size_t)((y << 6) | x) * 16;
        #pragma unroll
        for (int c = 0; c < 16; c++) {
            float v = ip[c];
            int wi = c * 9 + kk;
            a0 = fmaf(w3[wi],       v, a0);
            a1 = fmaf(w3[144 + wi], v, a1);
            a2 = fmaf(w3[288 + wi], v, a2);
        }
    }
    h3[(size_t)bp * 3 + 0] = a0 + b3[0];
    h3[(size_t)bp * 3 + 1] = a1 + b3[1];
    h3[(size_t)bp * 3 + 2] = a2 + b3[2];
}

// ---------------------------------------------------------------------------
// Conv4 (3x3, 3 -> 2) + softmax -> (score0, score1), FP32, numerics-free.
// ---------------------------------------------------------------------------
__global__ void k_score(const float* __restrict__ h3,
                        const float* __restrict__ w4,
                        const float* __restrict__ b4,
                        float2* __restrict__ score) {
    int bp = blockIdx.x * 256 + threadIdx.x;
    if (bp >= BP_N) return;
    int b = bp >> 12;
    int p = bp & 4095;
    int h = p >> 6, w = p & 63;
    const float* hb = h3 + (size_t)b * PIX * 3;

    float l0 = 0.f, l1 = 0.f;
    #pragma unroll
    for (int kk = 0; kk < 9; kk++) {
        int ky = kk / 3, kx = kk - ky * 3;
        int y = h + ky - 1, x = w + kx - 1;
        if ((unsigned)y >= 64u || (unsigned)x >= 64u) continue;
        const float* ip = hb + (size_t)((y << 6) | x) * 3;
        #pragma unroll
        for (int c = 0; c < 3; c++) {
            float v = ip[c];
            int wi = c * 9 + kk;
            l0 = fmaf(w4[wi],      v, l0);
            l1 = fmaf(w4[27 + wi], v, l1);
        }
    }
    l0 += b4[0];
    l1 += b4[1];

    float m  = fmaxf(l0, l1);
    float e0 = expf(l0 - m);
    float e1 = expf(l1 - m);
    float s  = e0 + e1;
    score[bp] = make_float2(e0 / s, e1 / s);
}

// ---------------------------------------------------------------------------
// Blend + on-the-fly NHWC->NCHW transpose of aligned.  Verbatim from R11.
// ---------------------------------------------------------------------------
__global__ void k_blend(const float* __restrict__ feat,
                        const float* __restrict__ alignedT,
                        const float2* __restrict__ score,
                        float* __restrict__ out) {
    __shared__ float tile[32][33];
    int b  = blockIdx.z;
    int p0 = blockIdx.x * 32;
    int c0 = blockIdx.y * 32;
    int tx = threadIdx.x;     // 32
    int ty = threadIdx.y;     // 8

    const float* at = alignedT + ((size_t)b << 20);
    #pragma unroll
    for (int i = 0; i < 4; i++) {
        int p = p0 + ty + i * 8;
        tile[ty + i * 8][tx] = at[((size_t)p << 8) + c0 + tx];
    }
    __syncthreads();

    int p = p0 + tx;
    float2 s = score[(b << 12) + p];
    #pragma unroll
    for (int i = 0; i < 4; i++) {
        int c = c0 + ty + i * 8;
        size_t idx = (((size_t)(b * 256 + c)) << 12) + p;
        out[idx] = __fadd_rn(__fmul_rn(s.x, feat[idx]),
                             __fmul_rn(s.y, tile[tx][ty + i * 8]));
    }
}

// ---------------------------------------------------------------------------
extern "C" void kernel_launch(void* const* d_in, const int* in_sizes, int n_in,
                              void* d_out, int out_size, void* d_ws, size_t ws_size,
                              hipStream_t stream) {
    const float* feat     = (const float*)d_in[0];
    const float* feat_ref = (const float*)d_in[1];
    const float* w1 = (const float*)d_in[2];
    const float* b1 = (const float*)d_in[3];
    const float* w2 = (const float*)d_in[4];
    const float* b2 = (const float*)d_in[5];
    const float* w3 = (const float*)d_in[6];
    const float* b3 = (const float*)d_in[7];
    const float* w4 = (const float*)d_in[8];
    const float* b4 = (const float*)d_in[9];
    float* out = (float*)d_out;

    const size_t NCP = (size_t)BATCH * CCH * PIX;   // 2,097,152
    char* wsb = (char*)d_ws;
    float*  featT    = (float*)wsb;   wsb += NCP * 4;               // 8 MB
    float*  refT     = (float*)wsb;   wsb += NCP * 4;               // 8 MB
    float*  alignedT = (float*)wsb;   wsb += NCP * 4;               // 8 MB
    float*  h1       = (float*)wsb;   wsb += NCP * 4;               // 8 MB
    float*  h2       = (float*)wsb;   wsb += (size_t)BP_N * 16 * 4;
    float*  h3       = (float*)wsb;   wsb += (size_t)BP_N * 3 * 4;
    float2* sc       = (float2*)wsb;  wsb += (size_t)BP_N * 8;
    float*  w2t      = (float*)wsb;   wsb += (size_t)16 * 256 * 9 * 4;
    float*  w1t      = (float*)wsb;   wsb += (size_t)512 * 256 * 4;

    dim3 tb(32, 8, 1);
    dim3 tg(PIX / 32, CCH / 32, BATCH);
    k_transpose<<<tg, tb, 0, stream>>>(feat, featT);
    k_transpose<<<tg, tb, 0, stream>>>(feat_ref, refT);
    k_w2t<<<144, 256, 0, stream>>>(w2, w2t);
    k_w1t<<<dim3(16, 8, 1), tb, 0, stream>>>(w1, w1t);

    k_corr_assemble<<<BP_N, 256, 0, stream>>>(featT, refT, alignedT);
    k_conv1<<<dim3(BP_N / 64, 256 / 64, 1), 256, 0, stream>>>(featT, alignedT, w1t, b1, h1);
    k_conv2<<<BP_N / 16, 256, 0, stream>>>(h1, w2t, b2, h2);
    k_conv3<<<BP_N / 256, 256, 0, stream>>>(h2, w3, b3, h3);
    k_score<<<BP_N / 256, 256, 0, stream>>>(h3, w4, b4, sc);
    k_blend<<<tg, tb, 0, stream>>>(feat, alignedT, sc, out);
}